// Round 9
// baseline (298.899 us; speedup 1.0000x reference)
//
#include <hip/hip_runtime.h>
#include <hip/hip_bf16.h>

#define D 64
#define SCAN_B 1024
#define NCOPY 8   // privatization copies; MUST match (blockIdx&7) in init & scatter

// ---- adaptive loads: index width (int32/int64) and float width (bf16/fp32) ----
__device__ __forceinline__ int load_idx(const void* p, long long i, int mode) {
  return mode ? (int)((const long long*)p)[i] : ((const int*)p)[i];
}
__device__ __forceinline__ float loadf(const void* p, long long i, int fm) {
  return fm ? ((const float*)p)[i]
            : __bfloat162float(((const __hip_bfloat16*)p)[i]);
}
// bf16 bit helpers
__device__ __forceinline__ unsigned short bf16bits(float v) {
  unsigned u = __float_as_uint(v);
  return (unsigned short)((u + 0x7FFFu + ((u >> 16) & 1u)) >> 16);  // RNE
}
__device__ __forceinline__ float bflo(unsigned u) { return __uint_as_float(u << 16); }
__device__ __forceinline__ float bfhi(unsigned u) { return __uint_as_float(u & 0xFFFF0000u); }

// ---------- detect dtypes ----------
__global__ void detect_kernel(const void* eidx, const void* etype, const void* ent0,
                              int* flags, int n_edges) {
  int lane = threadIdx.x;  // 64 threads, 1 wave
  long long tot_e = 2LL * n_edges;
  long long step_e = tot_e / 130; if (step_e < 1) step_e = 1;
  long long pos_e = 1 + 2LL * lane * step_e;
  int ve = (pos_e < tot_e) ? ((const int*)eidx)[pos_e] : 0;
  unsigned long long be = __ballot(ve != 0);

  long long tot_t = n_edges;
  long long step_t = tot_t / 130; if (step_t < 1) step_t = 1;
  long long pos_t = 1 + 2LL * lane * step_t;
  int vt = (pos_t < tot_t) ? ((const int*)etype)[pos_t] : 0;
  unsigned long long bt = __ballot(vt != 0);

  float a = __bfloat162float(((const __hip_bfloat16*)ent0)[lane]);
  unsigned long long bf = __ballot(!(fabsf(a) <= 64.0f));  // fp32-as-bf16 => huge/nan

  if (lane == 0) {
    flags[0] = (be == 0ULL) ? 1 : 0;   // edge_index is int64
    flags[1] = (bt == 0ULL) ? 1 : 0;   // edge_type is int64
    flags[3] = (bf != 0ULL) ? 1 : 0;   // float inputs are fp32
  }
}

// ---------- init: entC bf16 table, rel tables + out_rel base, privatized count ----------
__global__ __launch_bounds__(256) void init_kernel(
    const void* ent0, const void* rel0, const void* eidx,
    unsigned short* __restrict__ entC, float* __restrict__ relRaw,
    float* __restrict__ out_rel, int* __restrict__ cnt8,
    const int* __restrict__ flags,
    int ent_elems, int rel_elems, int n_ent, int n_edges) {
  int fm = flags[3];
  int i = blockIdx.x * blockDim.x + threadIdx.x;
  if (i < ent_elems) entC[i] = bf16bits(loadf(ent0, i, fm));
  if (i < rel_elems) {
    float v = loadf(rel0, i, fm);
    relRaw[i] = v;
    out_rel[i] = v;                       // residual base for relations
  }
  if (i < n_edges) {                      // privatized degree count (cnt8 pre-zeroed)
    int h = load_idx(eidx, i, flags[0]);
    h = min(max(h, 0), n_ent - 1);
    atomicAdd(&cnt8[(blockIdx.x & 7) * n_ent + h], 1);
  }
}

// ---------- scan A: exclusive scan over cnt8 in NATURAL (c-major) order ----------
// result -> cursor8: staging base for segment (c,h); staging is c-grouped so
// copy c's writes land in one contiguous region (XCD-local lines).
__global__ __launch_bounds__(SCAN_B) void scanA1_kernel(const int* cnt8, int* cursor8,
                                                        int* blockSums, int n) {
  __shared__ int tmp[SCAN_B];
  int tid = threadIdx.x;
  int gid = blockIdx.x * SCAN_B + tid;
  int v = (gid < n) ? cnt8[gid] : 0;
  tmp[tid] = v;
  __syncthreads();
  for (int off = 1; off < SCAN_B; off <<= 1) {
    int t = (tid >= off) ? tmp[tid - off] : 0;
    __syncthreads();
    tmp[tid] += t;
    __syncthreads();
  }
  if (gid < n) cursor8[gid] = tmp[tid] - v;  // exclusive
  if (tid == SCAN_B - 1) blockSums[blockIdx.x] = tmp[tid];
}

__global__ __launch_bounds__(SCAN_B) void scan2_kernel(int* bs, int nb) {
  __shared__ int tmp[SCAN_B];
  int tid = threadIdx.x;
  int v = (tid < nb) ? bs[tid] : 0;
  tmp[tid] = v;
  __syncthreads();
  for (int off = 1; off < SCAN_B; off <<= 1) {
    int t = (tid >= off) ? tmp[tid - off] : 0;
    __syncthreads();
    tmp[tid] += t;
    __syncthreads();
  }
  if (tid < nb) bs[tid] = tmp[tid] - v;
}

__global__ __launch_bounds__(SCAN_B) void scanA3_kernel(int* cursor8, const int* bs, int n) {
  int gid = blockIdx.x * SCAN_B + threadIdx.x;
  if (gid < n) cursor8[gid] += bs[blockIdx.x];
}

// ---------- row scan: deg[h] = sum_c cnt8[c][h]; exclusive scan -> rowinfo ----------
__global__ __launch_bounds__(SCAN_B) void rowscan1_kernel(const int* cnt8, int2* rowinfo,
                                                          int* blockSums, int n_ent) {
  __shared__ int tmp[SCAN_B];
  int tid = threadIdx.x;
  int gid = blockIdx.x * SCAN_B + tid;
  int deg = 0;
  if (gid < n_ent)
#pragma unroll
    for (int c = 0; c < NCOPY; ++c) deg += cnt8[c * n_ent + gid];
  tmp[tid] = deg;
  __syncthreads();
  for (int off = 1; off < SCAN_B; off <<= 1) {
    int t = (tid >= off) ? tmp[tid - off] : 0;
    __syncthreads();
    tmp[tid] += t;
    __syncthreads();
  }
  if (gid < n_ent) rowinfo[gid] = make_int2(tmp[tid] - deg, deg);  // partial excl, deg
  if (tid == SCAN_B - 1) blockSums[blockIdx.x] = tmp[tid];
}

__global__ __launch_bounds__(SCAN_B) void rowscan3_kernel(int2* rowinfo, const int* bs, int n_ent) {
  int gid = blockIdx.x * SCAN_B + threadIdx.x;
  if (gid < n_ent) rowinfo[gid].x += bs[blockIdx.x];
}

// ---------- scatter edges into c-major staging (XCD-local) + fused rel normalize ----------
__global__ __launch_bounds__(256) void scatter_kernel(
    const void* eidx, const void* etype, int* cursor8, int* staging,
    const int* flags, int n_edges, int n_ent, int edge_blocks,
    const float* __restrict__ relRaw, float* __restrict__ relN,
    float* __restrict__ out_rel, int n_rel) {
  if ((int)blockIdx.x < edge_blocks) {
    int e = blockIdx.x * blockDim.x + threadIdx.x;
    if (e < n_edges) {
      int m = flags[0];
      int h = load_idx(eidx, e, m);
      int t = load_idx(eidx, (long long)n_edges + e, m);
      int r = load_idx(etype, e, flags[1]);
      h = min(max(h, 0), n_ent - 1);
      t = min(max(t, 0), n_ent - 1);
      r = min(max(r, 0), 50);
      int c = blockIdx.x & 7;                      // same mapping as init count!
      int pos = atomicAdd(&cursor8[c * n_ent + h], 1);
      staging[pos] = t | (r << 20);                // tail < 2^20, type < 2^11
    }
  } else {
    // norm idempotent -> hop0 uses relRaw, hops1/2 use relN; rel_res = rel0 + 3*norm
    int i = (blockIdx.x - edge_blocks) * blockDim.x + threadIdx.x;
    int row = i >> 6;
    if (row >= n_rel) return;
    float v = relRaw[i];
    float ss = v * v;
    for (int o = 32; o > 0; o >>= 1) ss += __shfl_xor(ss, o, 64);
    float nv = (ss > 0.f) ? v * rsqrtf(ss) : 0.f;
    relN[i] = nv;
    out_rel[i] += 3.0f * nv;
  }
}

// ---------- merge: concatenate 8 staged segments per row into h-major csr ----------
// post-scatter cursor8[c][h] = base+cnt, so segment start = cursor8 - cnt8.
__global__ __launch_bounds__(256) void merge_kernel(
    const int* __restrict__ cnt8, const int* __restrict__ cursor8,
    const int* __restrict__ staging, const int2* __restrict__ rowinfo,
    int* __restrict__ csr, int n_ent) {
  int h = blockIdx.x * blockDim.x + threadIdx.x;
  if (h >= n_ent) return;
  int pos = rowinfo[h].x;
#pragma unroll
  for (int c = 0; c < NCOPY; ++c) {
    int b = c * n_ent + h;
    int cn = cnt8[b];
    int s = cursor8[b] - cn;
    for (int j = 0; j < cn; ++j) csr[pos++] = staging[s + j];
  }
}

// ---------- hop core: 4 rows/wave, 16 lanes/row, 4 dims/lane (unchanged, verified) ----------
__device__ __forceinline__ float4 hop_row(
    const unsigned short* __restrict__ src, const unsigned short* lds_rel,
    const int* __restrict__ csr, int beg, int num, int sub, int gbase) {
  float4 acc = make_float4(0.f, 0.f, 0.f, 0.f);
  for (int c = 0; c < num; c += 16) {
    int rem = min(num - c, 16);
    int pv = (sub < rem) ? csr[beg + c + sub] : 0;  // coalesced, 16 edges/group
    for (int j = 0; j < rem; j += 4) {
      uint2 sv[4], rv[4];
#pragma unroll
      for (int k = 0; k < 4; ++k) {
        int idx = j + k;
        int p = __shfl(pv, gbase + ((idx < rem) ? idx : 0), 64);
        int t = p & 0xFFFFF;
        int r = (p >> 20) & 0x7FF;
        sv[k] = *(const uint2*)(src + ((size_t)t << 6) + (sub << 2));   // 4 bf16 gather
        rv[k] = *(const uint2*)(lds_rel + (r << 6) + (sub << 2));       // 4 bf16 LDS
        if (idx >= rem) { sv[k].x = 0u; sv[k].y = 0u; }                 // mask tail
      }
#pragma unroll
      for (int k = 0; k < 4; ++k) {
        acc.x += bflo(sv[k].x) * bflo(rv[k].x);
        acc.y += bfhi(sv[k].x) * bfhi(rv[k].x);
        acc.z += bflo(sv[k].y) * bflo(rv[k].y);
        acc.w += bfhi(sv[k].y) * bfhi(rv[k].y);
      }
    }
  }
  return acc;
}

__device__ __forceinline__ float4 norm4(float4 acc) {
  float ss = acc.x * acc.x + acc.y * acc.y + acc.z * acc.z + acc.w * acc.w;
  for (int o = 8; o > 0; o >>= 1) ss += __shfl_xor(ss, o, 64);
  // l2_normalize(agg/denom) == l2_normalize(agg): denom positive scalar per row
  float inv = (ss > 0.f) ? rsqrtf(ss) : 0.f;
  return make_float4(acc.x * inv, acc.y * inv, acc.z * inv, acc.w * inv);
}

// hops 0/1: gather + normalize -> bf16 dst only
__global__ __launch_bounds__(256, 8) void hop_mid_kernel(
    const unsigned short* __restrict__ src, const float* __restrict__ relX,
    const int2* __restrict__ rowinfo, const int* __restrict__ csr,
    unsigned short* __restrict__ dst, int n_ent, int n_rel) {
  extern __shared__ unsigned short lds_rel[];
  for (int i = threadIdx.x; i < n_rel * D; i += blockDim.x)
    lds_rel[i] = bf16bits(relX[i]);
  __syncthreads();

  int lane = threadIdx.x & 63;
  int sub = lane & 15;
  int grp = (lane >> 4) & 3;
  int gbase = lane & 48;
  int wid = (blockIdx.x * blockDim.x + threadIdx.x) >> 6;
  int nw = (gridDim.x * blockDim.x) >> 6;

  for (int row = wid * 4 + grp; row < n_ent; row += nw * 4) {
    int2 ri = rowinfo[row];
    float4 val = norm4(hop_row(src, lds_rel, csr, ri.x, ri.y, sub, gbase));
    uint2 o;
    o.x = (unsigned)bf16bits(val.x) | ((unsigned)bf16bits(val.y) << 16);
    o.y = (unsigned)bf16bits(val.z) | ((unsigned)bf16bits(val.w) << 16);
    *(uint2*)(dst + ((size_t)row << 6) + (sub << 2)) = o;
  }
}

// hop 2: gather + normalize + full residual write (base + v0 + v1 + v2)
__global__ __launch_bounds__(256, 8) void hop_last_kernel(
    const unsigned short* __restrict__ src /*entA = v1*/,
    const unsigned short* __restrict__ v0tab /*entB*/,
    const float* __restrict__ relX,
    const int2* __restrict__ rowinfo, const int* __restrict__ csr,
    const void* __restrict__ ent0, const void* __restrict__ drug0,
    const int* __restrict__ flags,
    float* __restrict__ out_ent, float* __restrict__ out_drug,
    int n_ent, int n_drugs, int n_rel) {
  extern __shared__ unsigned short lds_rel[];
  for (int i = threadIdx.x; i < n_rel * D; i += blockDim.x)
    lds_rel[i] = bf16bits(relX[i]);
  __syncthreads();

  int fm = flags[3];
  int lane = threadIdx.x & 63;
  int sub = lane & 15;
  int grp = (lane >> 4) & 3;
  int gbase = lane & 48;
  int wid = (blockIdx.x * blockDim.x + threadIdx.x) >> 6;
  int nw = (gridDim.x * blockDim.x) >> 6;

  for (int row = wid * 4 + grp; row < n_ent; row += nw * 4) {
    int2 ri = rowinfo[row];
    float4 val = norm4(hop_row(src, lds_rel, csr, ri.x, ri.y, sub, gbase));
    size_t eoff = ((size_t)row << 6) + (sub << 2);
    uint2 b0 = *(const uint2*)(v0tab + eoff);   // hop0 value (bf16)
    uint2 b1 = *(const uint2*)(src + eoff);     // hop1 value (bf16)
    float4 s;
    s.x = val.x + bflo(b0.x) + bflo(b1.x);
    s.y = val.y + bfhi(b0.x) + bfhi(b1.x);
    s.z = val.z + bflo(b0.y) + bflo(b1.y);
    s.w = val.w + bfhi(b0.y) + bfhi(b1.y);
    float4 base;
    if (fm) base = *(const float4*)((const float*)ent0 + eoff);
    else {
      uint2 bb = *(const uint2*)((const unsigned short*)ent0 + eoff);
      base = make_float4(bflo(bb.x), bfhi(bb.x), bflo(bb.y), bfhi(bb.y));
    }
    *(float4*)(out_ent + eoff) =
        make_float4(base.x + s.x, base.y + s.y, base.z + s.z, base.w + s.w);
    if (row < n_drugs) {
      float4 db;
      if (fm) db = *(const float4*)((const float*)drug0 + eoff);
      else {
        uint2 bb = *(const uint2*)((const unsigned short*)drug0 + eoff);
        db = make_float4(bflo(bb.x), bfhi(bb.x), bflo(bb.y), bfhi(bb.y));
      }
      *(float4*)(out_drug + eoff) =
          make_float4(db.x + s.x, db.y + s.y, db.z + s.z, db.w + s.w);
    }
  }
}

__global__ void mini_flag_kernel(float* out, int hostbits) {
  if (blockIdx.x == 0 && threadIdx.x == 0)
    out[0] = 64.0f * (float)hostbits;
}

extern "C" void kernel_launch(void* const* d_in, const int* in_sizes, int n_in,
                              void* d_out, int out_size, void* d_ws, size_t ws_size,
                              hipStream_t stream) {
  const void* ent0  = d_in[0];
  const void* drug0 = d_in[1];
  const void* rel0  = d_in[2];
  const void* eidx  = d_in[3];
  const void* etype = d_in[4];
  float* out = (float*)d_out;          // output is fp32 (verified round 5)

  const int ent_elems  = in_sizes[0];
  const int drug_elems = in_sizes[1];
  const int rel_elems  = in_sizes[2];
  const int n_edges    = in_sizes[4];
  const int n_ent   = ent_elems / D;
  const int n_drugs = drug_elems / D;
  const int n_rel   = rel_elems / D;

  const int n8 = NCOPY * n_ent;
  int nScanBlocks = (n8 + SCAN_B - 1) / SCAN_B;
  int nRowBlocks  = (n_ent + SCAN_B - 1) / SCAN_B;

  int hostbits = 0;
  bool sizes_ok = (n_in == 5) &&
                  (in_sizes[3] == 2 * n_edges) &&
                  (out_size == ent_elems + drug_elems + rel_elems) &&
                  (ent_elems % D == 0) && (drug_elems % D == 0) &&
                  (rel_elems % D == 0) && (n_ent > 0) && (n_edges > 0) &&
                  (nScanBlocks <= SCAN_B) && (nRowBlocks <= SCAN_B);
  if (!sizes_ok) hostbits |= 32;

  char* w = (char*)d_ws;
  auto alloc = [&](size_t bytes) {
    char* p = w;
    w += (bytes + 255) / 256 * 256;
    return p;
  };
  int* flags      = (int*)alloc(256);
  int* blockSums  = (int*)alloc(4096);
  float* relRaw   = (float*)alloc((size_t)(rel_elems > 0 ? rel_elems : 1) * 4);
  float* relN     = (float*)alloc((size_t)(rel_elems > 0 ? rel_elems : 1) * 4);
  int2* rowinfo   = (int2*)alloc((size_t)(n_ent > 0 ? n_ent : 1) * 8);
  int* csr        = (int*)alloc((size_t)(n_edges > 0 ? n_edges : 1) * 4);
  unsigned short* entA = (unsigned short*)alloc((size_t)(ent_elems > 0 ? ent_elems : 1) * 2);
  unsigned short* entB = (unsigned short*)alloc((size_t)(ent_elems > 0 ? ent_elems : 1) * 2);
  // alias build scratch into entB dead space (first written at hop0):
  // entB bytes = 128*n_ent >= cnt8(32n) + cursor8(32n) + staging(4*n_edges=40n) = 104n. 
  int* cnt8    = (int*)entB;
  int* cursor8 = (int*)((char*)entB + (size_t)n8 * 4);
  int* staging = (int*)((char*)entB + (size_t)n8 * 8);
  unsigned short* entC = entA;  // entC (bf16 of ent0) dead before hop1 writes entA
  size_t needed = (size_t)(w - (char*)d_ws);
  if (ws_size < needed) hostbits |= 16;
  if ((size_t)ent_elems * 2 < (size_t)n8 * 8 + (size_t)n_edges * 4) hostbits |= 64;

  if (hostbits) {
    mini_flag_kernel<<<1, 64, 0, stream>>>(out, hostbits);
    return;
  }

  float* out_ent  = out;
  float* out_drug = out + ent_elems;
  float* out_rel  = out + ent_elems + drug_elems;

  hipMemsetAsync(cnt8, 0, (size_t)n8 * 4, stream);  // async, graph-capture safe

  detect_kernel<<<1, 64, 0, stream>>>(eidx, etype, ent0, flags, n_edges);

  int init_elems = ent_elems > n_edges ? ent_elems : n_edges;
  init_kernel<<<(init_elems + 255) / 256, 256, 0, stream>>>(
      ent0, rel0, eidx, entC, relRaw, out_rel, cnt8, flags,
      ent_elems, rel_elems, n_ent, n_edges);

  // scan A: staging bases in c-major order
  scanA1_kernel<<<nScanBlocks, SCAN_B, 0, stream>>>(cnt8, cursor8, blockSums, n8);
  scan2_kernel<<<1, SCAN_B, 0, stream>>>(blockSums, nScanBlocks);
  scanA3_kernel<<<nScanBlocks, SCAN_B, 0, stream>>>(cursor8, blockSums, n8);

  // row scan: rowinfo = {rowbeg, deg}
  rowscan1_kernel<<<nRowBlocks, SCAN_B, 0, stream>>>(cnt8, rowinfo, blockSums, n_ent);
  scan2_kernel<<<1, SCAN_B, 0, stream>>>(blockSums, nRowBlocks);
  rowscan3_kernel<<<nRowBlocks, SCAN_B, 0, stream>>>(rowinfo, blockSums, n_ent);

  int edge_blocks = (n_edges + 255) / 256;
  int rel_blocks  = (n_rel * D + 255) / 256;
  scatter_kernel<<<edge_blocks + rel_blocks, 256, 0, stream>>>(
      eidx, etype, cursor8, staging, flags, n_edges, n_ent, edge_blocks,
      relRaw, relN, out_rel, n_rel);

  merge_kernel<<<(n_ent + 255) / 256, 256, 0, stream>>>(
      cnt8, cursor8, staging, rowinfo, csr, n_ent);

  size_t lds_bytes = (size_t)n_rel * D * 2;  // bf16 rel table, 6.5 KB
  int hop_blocks = 2048;
  // hop0: entC(=entA) -> entB ; hop1: entB -> entA ; hop2: entA (+entB,ent0) -> out
  hop_mid_kernel<<<hop_blocks, 256, lds_bytes, stream>>>(
      entC, relRaw, rowinfo, csr, entB, n_ent, n_rel);
  hop_mid_kernel<<<hop_blocks, 256, lds_bytes, stream>>>(
      entB, relN, rowinfo, csr, entA, n_ent, n_rel);
  hop_last_kernel<<<hop_blocks, 256, lds_bytes, stream>>>(
      entA, entB, relN, rowinfo, csr, ent0, drug0, flags,
      out_ent, out_drug, n_ent, n_drugs, n_rel);
}

// Round 10
// 290.335 us; speedup vs baseline: 1.0295x; 1.0295x over previous
//
#include <hip/hip_runtime.h>
#include <hip/hip_bf16.h>

#define D 64
#define SCAN_B 1024
#define NCOPY 8   // privatization copies; MUST match (blockIdx&7) in init & scatter

// ---- adaptive loads: index width (int32/int64) and float width (bf16/fp32) ----
__device__ __forceinline__ int load_idx(const void* p, long long i, int mode) {
  return mode ? (int)((const long long*)p)[i] : ((const int*)p)[i];
}
__device__ __forceinline__ float loadf(const void* p, long long i, int fm) {
  return fm ? ((const float*)p)[i]
            : __bfloat162float(((const __hip_bfloat16*)p)[i]);
}
// bf16 bit helpers
__device__ __forceinline__ unsigned short bf16bits(float v) {
  unsigned u = __float_as_uint(v);
  return (unsigned short)((u + 0x7FFFu + ((u >> 16) & 1u)) >> 16);  // RNE
}
__device__ __forceinline__ float bflo(unsigned u) { return __uint_as_float(u << 16); }
__device__ __forceinline__ float bfhi(unsigned u) { return __uint_as_float(u & 0xFFFF0000u); }

// ---------- detect dtypes ----------
__global__ void detect_kernel(const void* eidx, const void* etype, const void* ent0,
                              int* flags, int n_edges) {
  int lane = threadIdx.x;  // 64 threads, 1 wave
  long long tot_e = 2LL * n_edges;
  long long step_e = tot_e / 130; if (step_e < 1) step_e = 1;
  long long pos_e = 1 + 2LL * lane * step_e;
  int ve = (pos_e < tot_e) ? ((const int*)eidx)[pos_e] : 0;
  unsigned long long be = __ballot(ve != 0);

  long long tot_t = n_edges;
  long long step_t = tot_t / 130; if (step_t < 1) step_t = 1;
  long long pos_t = 1 + 2LL * lane * step_t;
  int vt = (pos_t < tot_t) ? ((const int*)etype)[pos_t] : 0;
  unsigned long long bt = __ballot(vt != 0);

  float a = __bfloat162float(((const __hip_bfloat16*)ent0)[lane]);
  unsigned long long bf = __ballot(!(fabsf(a) <= 64.0f));  // fp32-as-bf16 => huge/nan

  if (lane == 0) {
    flags[0] = (be == 0ULL) ? 1 : 0;   // edge_index is int64
    flags[1] = (bt == 0ULL) ? 1 : 0;   // edge_type is int64
    flags[3] = (bf != 0ULL) ? 1 : 0;   // float inputs are fp32
  }
}

// ---------- init: privatized count + rel tables (+ entC conversion only if fp32) ----------
__global__ __launch_bounds__(256) void init_kernel(
    const void* ent0, const void* rel0, const void* eidx,
    unsigned short* __restrict__ entC, float* __restrict__ relRaw,
    float* __restrict__ out_rel, int* __restrict__ cnt8,
    const int* __restrict__ flags,
    int ent_elems, int rel_elems, int n_ent, int n_edges) {
  int fm = flags[3];
  int i = blockIdx.x * blockDim.x + threadIdx.x;
  if (fm) {                               // fp32 inputs: convert 8 elems/thread
    int i8 = i * 8;
    if (i8 < ent_elems) {
      float4 a = ((const float4*)ent0)[i * 2];
      float4 b = ((const float4*)ent0)[i * 2 + 1];
      uint4 o;
      o.x = (unsigned)bf16bits(a.x) | ((unsigned)bf16bits(a.y) << 16);
      o.y = (unsigned)bf16bits(a.z) | ((unsigned)bf16bits(a.w) << 16);
      o.z = (unsigned)bf16bits(b.x) | ((unsigned)bf16bits(b.y) << 16);
      o.w = (unsigned)bf16bits(b.z) | ((unsigned)bf16bits(b.w) << 16);
      ((uint4*)entC)[i] = o;
    }
  }                                       // bf16 inputs: hop0 reads ent0 in place
  if (i < rel_elems) {
    float v = loadf(rel0, i, fm);
    relRaw[i] = v;
    out_rel[i] = v;                       // residual base for relations
  }
  if (i < n_edges) {                      // privatized degree count (cnt8 pre-zeroed)
    int h = load_idx(eidx, i, flags[0]);
    h = min(max(h, 0), n_ent - 1);
    atomicAdd(&cnt8[(blockIdx.x & 7) * n_ent + h], 1);
  }
}

// ---------- scan A: exclusive scan over cnt8 in natural (c-major) order ----------
__global__ __launch_bounds__(SCAN_B) void scanA1_kernel(const int* cnt8, int* cursor8,
                                                        int* blockSums, int n) {
  __shared__ int tmp[SCAN_B];
  int tid = threadIdx.x;
  int gid = blockIdx.x * SCAN_B + tid;
  int v = (gid < n) ? cnt8[gid] : 0;
  tmp[tid] = v;
  __syncthreads();
  for (int off = 1; off < SCAN_B; off <<= 1) {
    int t = (tid >= off) ? tmp[tid - off] : 0;
    __syncthreads();
    tmp[tid] += t;
    __syncthreads();
  }
  if (gid < n) cursor8[gid] = tmp[tid] - v;  // exclusive
  if (tid == SCAN_B - 1) blockSums[blockIdx.x] = tmp[tid];
}

__global__ __launch_bounds__(SCAN_B) void scan2_kernel(int* bs, int nb) {
  __shared__ int tmp[SCAN_B];
  int tid = threadIdx.x;
  int v = (tid < nb) ? bs[tid] : 0;
  tmp[tid] = v;
  __syncthreads();
  for (int off = 1; off < SCAN_B; off <<= 1) {
    int t = (tid >= off) ? tmp[tid - off] : 0;
    __syncthreads();
    tmp[tid] += t;
    __syncthreads();
  }
  if (tid < nb) bs[tid] = tmp[tid] - v;
}

__global__ __launch_bounds__(SCAN_B) void scanA3_kernel(int* cursor8, const int* bs, int n) {
  int gid = blockIdx.x * SCAN_B + threadIdx.x;
  if (gid < n) cursor8[gid] += bs[blockIdx.x];
}

// ---------- row scan: deg[h] = sum_c cnt8[c][h]; exclusive scan -> rowinfo ----------
__global__ __launch_bounds__(SCAN_B) void rowscan1_kernel(const int* cnt8, int2* rowinfo,
                                                          int* blockSums, int n_ent) {
  __shared__ int tmp[SCAN_B];
  int tid = threadIdx.x;
  int gid = blockIdx.x * SCAN_B + tid;
  int deg = 0;
  if (gid < n_ent)
#pragma unroll
    for (int c = 0; c < NCOPY; ++c) deg += cnt8[c * n_ent + gid];
  tmp[tid] = deg;
  __syncthreads();
  for (int off = 1; off < SCAN_B; off <<= 1) {
    int t = (tid >= off) ? tmp[tid - off] : 0;
    __syncthreads();
    tmp[tid] += t;
    __syncthreads();
  }
  if (gid < n_ent) rowinfo[gid] = make_int2(tmp[tid] - deg, deg);  // partial excl, deg
  if (tid == SCAN_B - 1) blockSums[blockIdx.x] = tmp[tid];
}

__global__ __launch_bounds__(SCAN_B) void rowscan3_kernel(int2* rowinfo, const int* bs, int n_ent) {
  int gid = blockIdx.x * SCAN_B + threadIdx.x;
  if (gid < n_ent) rowinfo[gid].x += bs[blockIdx.x];
}

// ---------- scatter edges into c-major staging (XCD-local) + fused rel normalize ----------
__global__ __launch_bounds__(256) void scatter_kernel(
    const void* eidx, const void* etype, int* cursor8, int* staging,
    const int* flags, int n_edges, int n_ent, int edge_blocks,
    const float* __restrict__ relRaw, float* __restrict__ relN,
    float* __restrict__ out_rel, int n_rel) {
  if ((int)blockIdx.x < edge_blocks) {
    int e = blockIdx.x * blockDim.x + threadIdx.x;
    if (e < n_edges) {
      int m = flags[0];
      int h = load_idx(eidx, e, m);
      int t = load_idx(eidx, (long long)n_edges + e, m);
      int r = load_idx(etype, e, flags[1]);
      h = min(max(h, 0), n_ent - 1);
      t = min(max(t, 0), n_ent - 1);
      r = min(max(r, 0), 50);
      int c = blockIdx.x & 7;                      // same mapping as init count!
      int pos = atomicAdd(&cursor8[c * n_ent + h], 1);
      staging[pos] = t | (r << 20);                // tail < 2^20, type < 2^11
    }
  } else {
    // norm idempotent -> hop0 uses relRaw, hops1/2 use relN; rel_res = rel0 + 3*norm
    int i = (blockIdx.x - edge_blocks) * blockDim.x + threadIdx.x;
    int row = i >> 6;
    if (row >= n_rel) return;
    float v = relRaw[i];
    float ss = v * v;
    for (int o = 32; o > 0; o >>= 1) ss += __shfl_xor(ss, o, 64);
    float nv = (ss > 0.f) ? v * rsqrtf(ss) : 0.f;
    relN[i] = nv;
    out_rel[i] += 3.0f * nv;
  }
}

// ---------- merge: one thread per (c,h) segment (parallel, latency-friendly) ----------
// post-scatter cursor8[c][h] = base+cnt, so segment start = cursor8 - cnt8.
__global__ __launch_bounds__(256) void merge_kernel(
    const int* __restrict__ cnt8, const int* __restrict__ cursor8,
    const int* __restrict__ staging, const int2* __restrict__ rowinfo,
    int* __restrict__ csr, int n_ent, int n8) {
  int b = blockIdx.x * blockDim.x + threadIdx.x;
  if (b >= n8) return;
  int cn = cnt8[b];
  if (cn == 0) return;
  int c = b / n_ent;
  int h = b - c * n_ent;
  int src = cursor8[b] - cn;
  int prefix = 0;
  for (int cc = 0; cc < c; ++cc) prefix += cnt8[cc * n_ent + h];  // independent loads
  int dst = rowinfo[h].x + prefix;
  for (int j = 0; j < cn; ++j) csr[dst + j] = staging[src + j];
}

// ---------- hop core: 4 rows/wave, 16 lanes/row, 4 dims/lane, 8 outstanding gathers ----------
__device__ __forceinline__ float4 hop_row(
    const unsigned short* __restrict__ src, const unsigned short* lds_rel,
    const int* __restrict__ csr, int beg, int num, int sub, int gbase) {
  float4 acc = make_float4(0.f, 0.f, 0.f, 0.f);
  for (int c = 0; c < num; c += 16) {
    int rem = min(num - c, 16);
    int pv = (sub < rem) ? csr[beg + c + sub] : 0;  // coalesced, 16 edges/group
    for (int j = 0; j < rem; j += 8) {
      uint2 sv[8];
      int rr[8];
#pragma unroll
      for (int k = 0; k < 8; ++k) {
        int idx = j + k;
        int p = __shfl(pv, gbase + ((idx < rem) ? idx : 0), 64);
        int t = p & 0xFFFFF;
        rr[k] = (idx < rem) ? ((p >> 20) & 0x7FF) : -1;
        sv[k] = *(const uint2*)(src + ((size_t)t << 6) + (sub << 2));  // 8 independent gathers
      }
#pragma unroll
      for (int k = 0; k < 8; ++k) {
        uint2 rv;
        if (rr[k] >= 0) rv = *(const uint2*)(lds_rel + (rr[k] << 6) + (sub << 2));
        else { rv.x = 0u; rv.y = 0u; }              // mask tail via zero weight
        acc.x += bflo(sv[k].x) * bflo(rv.x);
        acc.y += bfhi(sv[k].x) * bfhi(rv.x);
        acc.z += bflo(sv[k].y) * bflo(rv.y);
        acc.w += bfhi(sv[k].y) * bfhi(rv.y);
      }
    }
  }
  return acc;
}

__device__ __forceinline__ float4 norm4(float4 acc) {
  float ss = acc.x * acc.x + acc.y * acc.y + acc.z * acc.z + acc.w * acc.w;
  for (int o = 8; o > 0; o >>= 1) ss += __shfl_xor(ss, o, 64);
  // l2_normalize(agg/denom) == l2_normalize(agg): denom positive scalar per row
  float inv = (ss > 0.f) ? rsqrtf(ss) : 0.f;
  return make_float4(acc.x * inv, acc.y * inv, acc.z * inv, acc.w * inv);
}

// hops 0/1: gather + normalize -> bf16 dst only
// first_hop: src = fm ? srcConv (entC) : srcRaw (ent0 in place, already bf16)
__global__ __launch_bounds__(256, 8) void hop_mid_kernel(
    const unsigned short* __restrict__ srcRaw, const unsigned short* __restrict__ srcConv,
    int first_hop, const float* __restrict__ relX,
    const int2* __restrict__ rowinfo, const int* __restrict__ csr,
    const int* __restrict__ flags,
    unsigned short* __restrict__ dst, int n_ent, int n_rel) {
  extern __shared__ unsigned short lds_rel[];
  for (int i = threadIdx.x; i < n_rel * D; i += blockDim.x)
    lds_rel[i] = bf16bits(relX[i]);
  __syncthreads();

  const unsigned short* src = (first_hop && flags[3]) ? srcConv : srcRaw;
  int lane = threadIdx.x & 63;
  int sub = lane & 15;
  int grp = (lane >> 4) & 3;
  int gbase = lane & 48;
  int wid = (blockIdx.x * blockDim.x + threadIdx.x) >> 6;
  int nw = (gridDim.x * blockDim.x) >> 6;

  for (int row = wid * 4 + grp; row < n_ent; row += nw * 4) {
    int2 ri = rowinfo[row];
    float4 val = norm4(hop_row(src, lds_rel, csr, ri.x, ri.y, sub, gbase));
    uint2 o;
    o.x = (unsigned)bf16bits(val.x) | ((unsigned)bf16bits(val.y) << 16);
    o.y = (unsigned)bf16bits(val.z) | ((unsigned)bf16bits(val.w) << 16);
    *(uint2*)(dst + ((size_t)row << 6) + (sub << 2)) = o;
  }
}

// hop 2: gather + normalize + full residual write (base + v0 + v1 + v2)
__global__ __launch_bounds__(256, 8) void hop_last_kernel(
    const unsigned short* __restrict__ src /*entA = v1*/,
    const unsigned short* __restrict__ v0tab /*entB*/,
    const float* __restrict__ relX,
    const int2* __restrict__ rowinfo, const int* __restrict__ csr,
    const void* __restrict__ ent0, const void* __restrict__ drug0,
    const int* __restrict__ flags,
    float* __restrict__ out_ent, float* __restrict__ out_drug,
    int n_ent, int n_drugs, int n_rel) {
  extern __shared__ unsigned short lds_rel[];
  for (int i = threadIdx.x; i < n_rel * D; i += blockDim.x)
    lds_rel[i] = bf16bits(relX[i]);
  __syncthreads();

  int fm = flags[3];
  int lane = threadIdx.x & 63;
  int sub = lane & 15;
  int grp = (lane >> 4) & 3;
  int gbase = lane & 48;
  int wid = (blockIdx.x * blockDim.x + threadIdx.x) >> 6;
  int nw = (gridDim.x * blockDim.x) >> 6;

  for (int row = wid * 4 + grp; row < n_ent; row += nw * 4) {
    int2 ri = rowinfo[row];
    float4 val = norm4(hop_row(src, lds_rel, csr, ri.x, ri.y, sub, gbase));
    size_t eoff = ((size_t)row << 6) + (sub << 2);
    uint2 b0 = *(const uint2*)(v0tab + eoff);   // hop0 value (bf16)
    uint2 b1 = *(const uint2*)(src + eoff);     // hop1 value (bf16)
    float4 s;
    s.x = val.x + bflo(b0.x) + bflo(b1.x);
    s.y = val.y + bfhi(b0.x) + bfhi(b1.x);
    s.z = val.z + bflo(b0.y) + bflo(b1.y);
    s.w = val.w + bfhi(b0.y) + bfhi(b1.y);
    float4 base;
    if (fm) base = *(const float4*)((const float*)ent0 + eoff);
    else {
      uint2 bb = *(const uint2*)((const unsigned short*)ent0 + eoff);
      base = make_float4(bflo(bb.x), bfhi(bb.x), bflo(bb.y), bfhi(bb.y));
    }
    *(float4*)(out_ent + eoff) =
        make_float4(base.x + s.x, base.y + s.y, base.z + s.z, base.w + s.w);
    if (row < n_drugs) {
      float4 db;
      if (fm) db = *(const float4*)((const float*)drug0 + eoff);
      else {
        uint2 bb = *(const uint2*)((const unsigned short*)drug0 + eoff);
        db = make_float4(bflo(bb.x), bfhi(bb.x), bflo(bb.y), bfhi(bb.y));
      }
      *(float4*)(out_drug + eoff) =
          make_float4(db.x + s.x, db.y + s.y, db.z + s.z, db.w + s.w);
    }
  }
}

__global__ void mini_flag_kernel(float* out, int hostbits) {
  if (blockIdx.x == 0 && threadIdx.x == 0)
    out[0] = 64.0f * (float)hostbits;
}

extern "C" void kernel_launch(void* const* d_in, const int* in_sizes, int n_in,
                              void* d_out, int out_size, void* d_ws, size_t ws_size,
                              hipStream_t stream) {
  const void* ent0  = d_in[0];
  const void* drug0 = d_in[1];
  const void* rel0  = d_in[2];
  const void* eidx  = d_in[3];
  const void* etype = d_in[4];
  float* out = (float*)d_out;          // output is fp32 (verified round 5)

  const int ent_elems  = in_sizes[0];
  const int drug_elems = in_sizes[1];
  const int rel_elems  = in_sizes[2];
  const int n_edges    = in_sizes[4];
  const int n_ent   = ent_elems / D;
  const int n_drugs = drug_elems / D;
  const int n_rel   = rel_elems / D;

  const int n8 = NCOPY * n_ent;
  int nScanBlocks = (n8 + SCAN_B - 1) / SCAN_B;
  int nRowBlocks  = (n_ent + SCAN_B - 1) / SCAN_B;

  int hostbits = 0;
  bool sizes_ok = (n_in == 5) &&
                  (in_sizes[3] == 2 * n_edges) &&
                  (out_size == ent_elems + drug_elems + rel_elems) &&
                  (ent_elems % D == 0) && (drug_elems % D == 0) &&
                  (rel_elems % D == 0) && (n_ent > 0) && (n_edges > 0) &&
                  (nScanBlocks <= SCAN_B) && (nRowBlocks <= SCAN_B);
  if (!sizes_ok) hostbits |= 32;

  char* w = (char*)d_ws;
  auto alloc = [&](size_t bytes) {
    char* p = w;
    w += (bytes + 255) / 256 * 256;
    return p;
  };
  int* flags      = (int*)alloc(256);
  int* blockSums  = (int*)alloc(4096);
  float* relRaw   = (float*)alloc((size_t)(rel_elems > 0 ? rel_elems : 1) * 4);
  float* relN     = (float*)alloc((size_t)(rel_elems > 0 ? rel_elems : 1) * 4);
  int2* rowinfo   = (int2*)alloc((size_t)(n_ent > 0 ? n_ent : 1) * 8);
  int* csr        = (int*)alloc((size_t)(n_edges > 0 ? n_edges : 1) * 4);
  unsigned short* entA = (unsigned short*)alloc((size_t)(ent_elems > 0 ? ent_elems : 1) * 2);
  unsigned short* entB = (unsigned short*)alloc((size_t)(ent_elems > 0 ? ent_elems : 1) * 2);
  // alias build scratch into entB dead space (first written at hop0):
  // entB bytes = 128*n_ent >= cnt8(32n) + cursor8(32n) + staging(4*n_edges=40n) = 104n.
  int* cnt8    = (int*)entB;
  int* cursor8 = (int*)((char*)entB + (size_t)n8 * 4);
  int* staging = (int*)((char*)entB + (size_t)n8 * 8);
  unsigned short* entC = entA;  // entC (bf16 of fp32 ent0) dead before hop1 writes entA
  size_t needed = (size_t)(w - (char*)d_ws);
  if (ws_size < needed) hostbits |= 16;
  if ((size_t)ent_elems * 2 < (size_t)n8 * 8 + (size_t)n_edges * 4) hostbits |= 64;

  if (hostbits) {
    mini_flag_kernel<<<1, 64, 0, stream>>>(out, hostbits);
    return;
  }

  float* out_ent  = out;
  float* out_drug = out + ent_elems;
  float* out_rel  = out + ent_elems + drug_elems;

  hipMemsetAsync(cnt8, 0, (size_t)n8 * 4, stream);  // async, graph-capture safe

  detect_kernel<<<1, 64, 0, stream>>>(eidx, etype, ent0, flags, n_edges);

  int conv_threads = (ent_elems + 7) / 8;
  int init_threads = conv_threads > n_edges ? conv_threads : n_edges;
  init_kernel<<<(init_threads + 255) / 256, 256, 0, stream>>>(
      ent0, rel0, eidx, entC, relRaw, out_rel, cnt8, flags,
      ent_elems, rel_elems, n_ent, n_edges);

  // scan A: staging bases in c-major order
  scanA1_kernel<<<nScanBlocks, SCAN_B, 0, stream>>>(cnt8, cursor8, blockSums, n8);
  scan2_kernel<<<1, SCAN_B, 0, stream>>>(blockSums, nScanBlocks);
  scanA3_kernel<<<nScanBlocks, SCAN_B, 0, stream>>>(cursor8, blockSums, n8);

  // row scan: rowinfo = {rowbeg, deg}
  rowscan1_kernel<<<nRowBlocks, SCAN_B, 0, stream>>>(cnt8, rowinfo, blockSums, n_ent);
  scan2_kernel<<<1, SCAN_B, 0, stream>>>(blockSums, nRowBlocks);
  rowscan3_kernel<<<nRowBlocks, SCAN_B, 0, stream>>>(rowinfo, blockSums, n_ent);

  int edge_blocks = (n_edges + 255) / 256;
  int rel_blocks  = (n_rel * D + 255) / 256;
  scatter_kernel<<<edge_blocks + rel_blocks, 256, 0, stream>>>(
      eidx, etype, cursor8, staging, flags, n_edges, n_ent, edge_blocks,
      relRaw, relN, out_rel, n_rel);

  merge_kernel<<<(n8 + 255) / 256, 256, 0, stream>>>(
      cnt8, cursor8, staging, rowinfo, csr, n_ent, n8);

  size_t lds_bytes = (size_t)n_rel * D * 2;  // bf16 rel table, 6.5 KB
  int hop_blocks = 2048;
  // hop0: ent0/entC -> entB ; hop1: entB -> entA ; hop2: entA (+entB,ent0) -> out
  hop_mid_kernel<<<hop_blocks, 256, lds_bytes, stream>>>(
      (const unsigned short*)ent0, entC, 1, relRaw, rowinfo, csr, flags,
      entB, n_ent, n_rel);
  hop_mid_kernel<<<hop_blocks, 256, lds_bytes, stream>>>(
      entB, entC, 0, relN, rowinfo, csr, flags, entA, n_ent, n_rel);
  hop_last_kernel<<<hop_blocks, 256, lds_bytes, stream>>>(
      entA, entB, relN, rowinfo, csr, ent0, drug0, flags,
      out_ent, out_drug, n_ent, n_drugs, n_rel);
}